// Round 11
// baseline (360.926 us; speedup 1.0000x reference)
//
#include <hip/hip_runtime.h>
#include <hip/hip_bf16.h>

#define N_NODES 100000
#define N_EDGES 1600000
#define D_IN 64
#define D_OUT 64
#define E_DIM 32
#define KCAT 288            // 3*64 (S buckets) + 3*32 (T buckets)
#define NK (4 * N_NODES)    // sort keys: 4*dst + etype (slot 3 unused -> count 0)
#define NBCHUNK 391         // ceil(NK / 1024)

typedef unsigned long long u64;
typedef __hip_bfloat16 bf16;
typedef unsigned char u8;

__device__ __forceinline__ float bflo(unsigned u) {
    union { unsigned v; float f; } x; x.v = u << 16; return x.f;
}
__device__ __forceinline__ float bfhi(unsigned u) {
    union { unsigned v; float f; } x; x.v = u & 0xffff0000u; return x.f;
}

// ---------------------------------------------------------------------------
// zero helper (capture-safe)
// ---------------------------------------------------------------------------
__global__ __launch_bounds__(256) void zero_buf(float4* __restrict__ p, long n4) {
    long i = (long)blockIdx.x * 256 + threadIdx.x;
    long stride = (long)gridDim.x * 256;
    float4 z = make_float4(0.f, 0.f, 0.f, 0.f);
    for (; i < n4; i += stride) p[i] = z;
}

// ---------------------------------------------------------------------------
// node_xform_g: GEMM-style microtile (64 nodes x 64 cols / block).
// ---------------------------------------------------------------------------
__global__ __launch_bounds__(256) void node_xform_g(const float* __restrict__ nf,
                                                    const float* __restrict__ Wn,
                                                    const int* __restrict__ ntype,
                                                    bf16* __restrict__ xout) {
    __shared__ float Ws[2 * 64 * 64];   // [t][k][j], 32 KB
    __shared__ float As[64][65];        // [row][k], padded
    int tid = threadIdx.x;
    int n0 = blockIdx.x * 64;
    for (int i = tid; i < 2 * 64 * 64; i += 256) Ws[i] = Wn[i];
#pragma unroll
    for (int i = 0; i < 4; ++i) {
        int f = (i * 256 + tid) * 4;
        int r = f >> 6, c = f & 63;
        int n = n0 + r;
        float4 v = (n < N_NODES) ? *(const float4*)&nf[(size_t)n * 64 + c]
                                 : make_float4(0.f, 0.f, 0.f, 0.f);
        As[r][c + 0] = v.x; As[r][c + 1] = v.y; As[r][c + 2] = v.z; As[r][c + 3] = v.w;
    }
    __syncthreads();
    int tx = tid & 15, ty = tid >> 4;
    int r0 = n0 + ty * 4;
    int t0 = (r0 + 0 < N_NODES) ? ntype[r0 + 0] : 0;
    int t1 = (r0 + 1 < N_NODES) ? ntype[r0 + 1] : 0;
    int t2 = (r0 + 2 < N_NODES) ? ntype[r0 + 2] : 0;
    int t3 = (r0 + 3 < N_NODES) ? ntype[r0 + 3] : 0;
    float4 acc0 = {0,0,0,0}, acc1 = {0,0,0,0}, acc2 = {0,0,0,0}, acc3 = {0,0,0,0};
#pragma unroll 8
    for (int k = 0; k < 64; ++k) {
        float4 w0 = *(const float4*)&Ws[k * 64 + tx * 4];
        float4 w1 = *(const float4*)&Ws[4096 + k * 64 + tx * 4];
        float a0 = As[ty * 4 + 0][k];
        float a1 = As[ty * 4 + 1][k];
        float a2 = As[ty * 4 + 2][k];
        float a3 = As[ty * 4 + 3][k];
        float4 wa = t0 ? w1 : w0;
        float4 wb = t1 ? w1 : w0;
        float4 wc = t2 ? w1 : w0;
        float4 wd = t3 ? w1 : w0;
        acc0.x = fmaf(a0, wa.x, acc0.x); acc0.y = fmaf(a0, wa.y, acc0.y);
        acc0.z = fmaf(a0, wa.z, acc0.z); acc0.w = fmaf(a0, wa.w, acc0.w);
        acc1.x = fmaf(a1, wb.x, acc1.x); acc1.y = fmaf(a1, wb.y, acc1.y);
        acc1.z = fmaf(a1, wb.z, acc1.z); acc1.w = fmaf(a1, wb.w, acc1.w);
        acc2.x = fmaf(a2, wc.x, acc2.x); acc2.y = fmaf(a2, wc.y, acc2.y);
        acc2.z = fmaf(a2, wc.z, acc2.z); acc2.w = fmaf(a2, wc.w, acc2.w);
        acc3.x = fmaf(a3, wd.x, acc3.x); acc3.y = fmaf(a3, wd.y, acc3.y);
        acc3.z = fmaf(a3, wd.z, acc3.z); acc3.w = fmaf(a3, wd.w, acc3.w);
    }
#pragma unroll
    for (int r = 0; r < 4; ++r) {
        int n = r0 + r;
        if (n < N_NODES) {
            float4 a = (r == 0) ? acc0 : (r == 1) ? acc1 : (r == 2) ? acc2 : acc3;
            union { bf16 h[4]; uint2 u; } pk;
            pk.h[0] = __float2bfloat16(a.x); pk.h[1] = __float2bfloat16(a.y);
            pk.h[2] = __float2bfloat16(a.z); pk.h[3] = __float2bfloat16(a.w);
            *(uint2*)&xout[(size_t)n * 64 + tx * 4] = pk.u;
        }
    }
}

// ---------------------------------------------------------------------------
// count + rank: rank[i] = arrival order within key (4*dst+etype).
// ---------------------------------------------------------------------------
__global__ __launch_bounds__(256) void count_rank(const int* __restrict__ eidx,
                                                  const int* __restrict__ etype,
                                                  int* __restrict__ cnt,
                                                  u8* __restrict__ rank) {
    int i = blockIdx.x * 256 + threadIdx.x;   // edge quad id
    if (i >= N_EDGES / 4) return;
    int4 d = ((const int4*)(eidx + N_EDGES))[i];
    int4 t = ((const int4*)etype)[i];
    int r0 = atomicAdd(&cnt[4 * d.x + t.x], 1);
    int r1 = atomicAdd(&cnt[4 * d.y + t.y], 1);
    int r2 = atomicAdd(&cnt[4 * d.z + t.z], 1);
    int r3 = atomicAdd(&cnt[4 * d.w + t.w], 1);
    ((uchar4*)rank)[i] = make_uchar4((u8)r0, (u8)r1, (u8)r2, (u8)r3);
}

__global__ __launch_bounds__(256) void scan_a(const int* __restrict__ cnt,
                                              int* __restrict__ partials) {
    __shared__ int ws[4];
    int b = blockIdx.x, tid = threadIdx.x, lane = tid & 63, wid = tid >> 6;
    int i0 = b * 1024 + tid * 4;
    int s = 0;
#pragma unroll
    for (int k = 0; k < 4; ++k) { int i = i0 + k; if (i < NK) s += cnt[i]; }
#pragma unroll
    for (int d = 32; d > 0; d >>= 1) s += __shfl_down(s, d);
    if (lane == 0) ws[wid] = s;
    __syncthreads();
    if (tid == 0) partials[b] = ws[0] + ws[1] + ws[2] + ws[3];
}

__global__ __launch_bounds__(512) void scan_b(int* __restrict__ partials) {
    __shared__ int s[512];
    int tid = threadIdx.x;
    int v = (tid < NBCHUNK) ? partials[tid] : 0;
    s[tid] = v;
    __syncthreads();
    for (int d = 1; d < 512; d <<= 1) {
        int u = (tid >= d) ? s[tid - d] : 0;
        __syncthreads();
        s[tid] += u;
        __syncthreads();
    }
    if (tid < NBCHUNK) partials[tid] = s[tid] - v;   // exclusive
}

__global__ __launch_bounds__(256) void scan_c(const int* __restrict__ cnt,
                                              const int* __restrict__ partials,
                                              int* __restrict__ offs) {
    __shared__ int wsum[4];
    int b = blockIdx.x, tid = threadIdx.x, lane = tid & 63, wid = tid >> 6;
    int i0 = b * 1024 + tid * 4;
    int c0 = (i0 + 0 < NK) ? cnt[i0 + 0] : 0;
    int c1 = (i0 + 1 < NK) ? cnt[i0 + 1] : 0;
    int c2 = (i0 + 2 < NK) ? cnt[i0 + 2] : 0;
    int c3 = (i0 + 3 < NK) ? cnt[i0 + 3] : 0;
    int lsum = c0 + c1 + c2 + c3;
    int v = lsum;
#pragma unroll
    for (int d = 1; d < 64; d <<= 1) {
        int u = __shfl_up(v, d);
        if (lane >= d) v += u;
    }
    int wexcl = v - lsum;
    if (lane == 63) wsum[wid] = v;
    __syncthreads();
    int bexcl = 0;
    for (int w = 0; w < wid; ++w) bexcl += wsum[w];
    int base = partials[b] + bexcl + wexcl;
    if (i0 + 0 < NK) offs[i0 + 0] = base; base += c0;
    if (i0 + 1 < NK) offs[i0 + 1] = base; base += c1;
    if (i0 + 2 < NK) offs[i0 + 2] = base; base += c2;
    if (i0 + 3 < NK) offs[i0 + 3] = base;
}

// ---------------------------------------------------------------------------
// place_pay: 8B payload scatter (pos = offs[key]+rank, no atomics), x4 vec.
// ---------------------------------------------------------------------------
__global__ __launch_bounds__(256) void place_pay(const int* __restrict__ eidx,
                                                 const int* __restrict__ etype,
                                                 const u8* __restrict__ rank,
                                                 const int* __restrict__ offs,
                                                 u64* __restrict__ pay) {
    int i = blockIdx.x * 256 + threadIdx.x;   // edge quad id
    if (i >= N_EDGES / 4) return;
    int4 d = ((const int4*)(eidx + N_EDGES))[i];
    int4 s = ((const int4*)eidx)[i];
    int4 t = ((const int4*)etype)[i];
    uchar4 r = ((const uchar4*)rank)[i];
    unsigned e0 = 4u * (unsigned)i;
    pay[offs[4 * d.x + t.x] + (int)r.x] = (u64)(unsigned)s.x | ((u64)(e0 + 0) << 32);
    pay[offs[4 * d.y + t.y] + (int)r.y] = (u64)(unsigned)s.y | ((u64)(e0 + 1) << 32);
    pay[offs[4 * d.z + t.z] + (int)r.z] = (u64)(unsigned)s.z | ((u64)(e0 + 2) << 32);
    pay[offs[4 * d.w + t.w] + (int)r.w] = (u64)(unsigned)s.w | ((u64)(e0 + 3) << 32);
}

// ---------------------------------------------------------------------------
// aggregate_g: wave/node. Per 8 edges: ONE uint4 wave-load covers all 8
// xout rows (lane group g=lane>>3 -> edge j+g, lane&7 -> 16B of the 128B
// row) and ONE float4 wave-load covers all 8 ef rows. Per-lane edge ids via
// __shfl(plo, j+g) (ds_bpermute). Accumulate {total, seg0, seg2} per lane;
// seg1 reconstructed at the end. Fold across groups with shfl_down(8/16/32).
// Zero atomics.
// ---------------------------------------------------------------------------
__global__ __launch_bounds__(256) void aggregate_g(const u64* __restrict__ pay,
                                                   const int* __restrict__ offs,
                                                   const bf16* __restrict__ xout,
                                                   const float* __restrict__ ef,
                                                   bf16* __restrict__ B) {
    int wid = threadIdx.x >> 6, lane = threadIdx.x & 63;
    int n = blockIdx.x * 4 + wid;
    if (n >= N_NODES) return;
    int4 o = ((const int4*)offs)[n];           // starts t0,t1,t2, end
    int beg = __builtin_amdgcn_readfirstlane(o.x);
    int y   = __builtin_amdgcn_readfirstlane(o.y);
    int z   = __builtin_amdgcn_readfirstlane(o.z);
    int end = __builtin_amdgcn_readfirstlane(o.w);
    int g = lane >> 3, l = lane & 7;

    float xt[8] = {}, x0[8] = {}, x2[8] = {};
    float et[4] = {}, e0a[4] = {}, e2a[4] = {};

    for (int base = beg; base < end; base += 64) {
        int m = end - base; if (m > 64) m = 64;
        u64 p = (lane < m) ? pay[base + lane] : 0ull;
        int plo = (int)(unsigned)p;            // src
        int phi = (int)(unsigned)(p >> 32);    // edge id
        for (int j = 0; j < m; j += 8) {
            int sg = __shfl(plo, j + g);       // per-lane src (bpermute)
            int eg = __shfl(phi, j + g);       // per-lane edge id
            uint4  xv = *(const uint4*)(xout + (size_t)sg * 64 + l * 8);
            float4 ev = *(const float4*)(ef + (size_t)eg * 32 + l * 4);
            int idx = base + j + g;
            bool inv = idx < end;
            bool in0 = idx < y;
            bool in2 = (idx >= z) && inv;
            float xf[8] = { bflo(xv.x), bfhi(xv.x), bflo(xv.y), bfhi(xv.y),
                            bflo(xv.z), bfhi(xv.z), bflo(xv.w), bfhi(xv.w) };
#pragma unroll
            for (int c = 0; c < 8; ++c) {
                float f = inv ? xf[c] : 0.f;
                xt[c] += f;
                x0[c] += in0 ? f : 0.f;
                x2[c] += in2 ? f : 0.f;
            }
            float ef4[4] = { ev.x, ev.y, ev.z, ev.w };
#pragma unroll
            for (int c = 0; c < 4; ++c) {
                float f = inv ? ef4[c] : 0.f;
                et[c]  += f;
                e0a[c] += in0 ? f : 0.f;
                e2a[c] += in2 ? f : 0.f;
            }
        }
    }
    // fold across the 8 lane-groups (lanes 0..7 end up with totals)
#pragma unroll
    for (int c = 0; c < 8; ++c) {
        xt[c] += __shfl_down(xt[c], 8);  xt[c] += __shfl_down(xt[c], 16);  xt[c] += __shfl_down(xt[c], 32);
        x0[c] += __shfl_down(x0[c], 8);  x0[c] += __shfl_down(x0[c], 16);  x0[c] += __shfl_down(x0[c], 32);
        x2[c] += __shfl_down(x2[c], 8);  x2[c] += __shfl_down(x2[c], 16);  x2[c] += __shfl_down(x2[c], 32);
    }
#pragma unroll
    for (int c = 0; c < 4; ++c) {
        et[c]  += __shfl_down(et[c], 8);  et[c]  += __shfl_down(et[c], 16);  et[c]  += __shfl_down(et[c], 32);
        e0a[c] += __shfl_down(e0a[c], 8); e0a[c] += __shfl_down(e0a[c], 16); e0a[c] += __shfl_down(e0a[c], 32);
        e2a[c] += __shfl_down(e2a[c], 8); e2a[c] += __shfl_down(e2a[c], 16); e2a[c] += __shfl_down(e2a[c], 32);
    }

    if (lane < 8) {
        bf16* Bn = B + (size_t)n * KCAT;
        union { bf16 h[8]; uint4 u; } pk;
#pragma unroll
        for (int c = 0; c < 8; ++c) pk.h[c] = __float2bfloat16(x0[c]);
        *(uint4*)&Bn[8 * lane] = pk.u;
#pragma unroll
        for (int c = 0; c < 8; ++c) pk.h[c] = __float2bfloat16(xt[c] - x0[c] - x2[c]);
        *(uint4*)&Bn[64 + 8 * lane] = pk.u;
#pragma unroll
        for (int c = 0; c < 8; ++c) pk.h[c] = __float2bfloat16(x2[c]);
        *(uint4*)&Bn[128 + 8 * lane] = pk.u;
        union { bf16 h[4]; uint2 u; } pe;
#pragma unroll
        for (int c = 0; c < 4; ++c) pe.h[c] = __float2bfloat16(e0a[c]);
        *(uint2*)&Bn[192 + 4 * lane] = pe.u;
#pragma unroll
        for (int c = 0; c < 4; ++c) pe.h[c] = __float2bfloat16(et[c] - e0a[c] - e2a[c]);
        *(uint2*)&Bn[224 + 4 * lane] = pe.u;
#pragma unroll
        for (int c = 0; c < 4; ++c) pe.h[c] = __float2bfloat16(e2a[c]);
        *(uint2*)&Bn[256 + 4 * lane] = pe.u;
    }
}

// ---------------------------------------------------------------------------
// K3: out = B(bf16) @ Wcat(fp32), Wcat[288][64] remapped from W_msg on load.
// ---------------------------------------------------------------------------
__global__ __launch_bounds__(256) void final_gemm(const bf16* __restrict__ B,
                                                  const float* __restrict__ Wm,
                                                  float* __restrict__ out) {
    __shared__ float As[64][33];   // +1 pad
    __shared__ float Ws[32][64];
    int tid = threadIdx.x;
    int n0 = blockIdx.x * 64;
    int tx = tid & 15;
    int ty = tid >> 4;
    float acc[4][4] = {};

    for (int k0 = 0; k0 < KCAT; k0 += 32) {
#pragma unroll
        for (int i = 0; i < 8; ++i) {
            int f = i * 256 + tid;
            int r = f >> 5, cc = f & 31;
            int n = n0 + r;
            As[r][cc] = (n < N_NODES) ? __bfloat162float(B[(size_t)n * KCAT + k0 + cc]) : 0.f;
        }
#pragma unroll
        for (int i = 0; i < 8; ++i) {
            int f = i * 256 + tid;
            int kk = f >> 6, j = f & 63;
            int r = k0 + kk;
            int t, kin;
            if (r < 192) { t = r >> 6; kin = r & 63; }
            else         { int q = r - 192; t = q >> 5; kin = 64 + (q & 31); }
            Ws[kk][j] = Wm[(t * 96 + kin) * 64 + j];
        }
        __syncthreads();
#pragma unroll
        for (int kk = 0; kk < 32; ++kk) {
            float a0 = As[ty * 4 + 0][kk];
            float a1 = As[ty * 4 + 1][kk];
            float a2 = As[ty * 4 + 2][kk];
            float a3 = As[ty * 4 + 3][kk];
            float4 w = *(const float4*)&Ws[kk][tx * 4];
            acc[0][0] = fmaf(a0, w.x, acc[0][0]); acc[0][1] = fmaf(a0, w.y, acc[0][1]);
            acc[0][2] = fmaf(a0, w.z, acc[0][2]); acc[0][3] = fmaf(a0, w.w, acc[0][3]);
            acc[1][0] = fmaf(a1, w.x, acc[1][0]); acc[1][1] = fmaf(a1, w.y, acc[1][1]);
            acc[1][2] = fmaf(a1, w.z, acc[1][2]); acc[1][3] = fmaf(a1, w.w, acc[1][3]);
            acc[2][0] = fmaf(a2, w.x, acc[2][0]); acc[2][1] = fmaf(a2, w.y, acc[2][1]);
            acc[2][2] = fmaf(a2, w.z, acc[2][2]); acc[2][3] = fmaf(a2, w.w, acc[2][3]);
            acc[3][0] = fmaf(a3, w.x, acc[3][0]); acc[3][1] = fmaf(a3, w.y, acc[3][1]);
            acc[3][2] = fmaf(a3, w.z, acc[3][2]); acc[3][3] = fmaf(a3, w.w, acc[3][3]);
        }
        __syncthreads();
    }
#pragma unroll
    for (int r = 0; r < 4; ++r) {
        int n = n0 + ty * 4 + r;
        if (n < N_NODES) {
            float4 v = make_float4(acc[r][0], acc[r][1], acc[r][2], acc[r][3]);
            *(float4*)&out[(size_t)n * 64 + tx * 4] = v;
        }
    }
}

// ---------------------------------------------------------------------------
// Fallback (ws tiny): direct wave-per-edge, fp32.
// ---------------------------------------------------------------------------
__global__ __launch_bounds__(256) void fallback_edge(const float* __restrict__ nf,
                                                     const float* __restrict__ ef,
                                                     const float* __restrict__ Wn,
                                                     const float* __restrict__ Wm,
                                                     const int* __restrict__ ntype,
                                                     const int* __restrict__ etype,
                                                     const int* __restrict__ eidx,
                                                     float* __restrict__ out) {
    __shared__ float wn[2 * 64 * 64];
    __shared__ float wm[3 * 96 * 64];
    for (int i = threadIdx.x; i < 2 * 64 * 64; i += 256) wn[i] = Wn[i];
    for (int i = threadIdx.x; i < 3 * 96 * 64; i += 256) wm[i] = Wm[i];
    __syncthreads();
    int wid = threadIdx.x >> 6, lane = threadIdx.x & 63;
    for (int e = blockIdx.x * 4 + wid; e < N_EDGES; e += gridDim.x * 4) {
        int t = etype[e];
        int s = eidx[e];
        int d = eidx[N_EDGES + e];
        int nt = ntype[s];
        float xs = nf[(long)s * 64 + lane];
        const float* wcol = &wn[nt * 4096 + lane];
        float xo = 0.f;
#pragma unroll 16
        for (int k = 0; k < 64; ++k) xo = fmaf(__shfl(xs, k), wcol[k * 64], xo);
        float ev = ef[(long)e * 32 + (lane & 31)];
        const float* mcol = &wm[t * 96 * 64 + lane];
        float m = 0.f;
#pragma unroll 16
        for (int k = 0; k < 64; ++k) m = fmaf(__shfl(xo, k), mcol[k * 64], m);
#pragma unroll 8
        for (int k = 0; k < 32; ++k) m = fmaf(__shfl(ev, k), mcol[(64 + k) * 64], m);
        atomicAdd(&out[(long)d * 64 + lane], m);
    }
}

// ---------------------------------------------------------------------------
extern "C" void kernel_launch(void* const* d_in, const int* in_sizes, int n_in,
                              void* d_out, int out_size, void* d_ws, size_t ws_size,
                              hipStream_t stream) {
    const float* nf    = (const float*)d_in[0];
    const float* ef    = (const float*)d_in[1];
    const float* Wn    = (const float*)d_in[2];
    const float* Wm    = (const float*)d_in[3];
    const int*   ntype = (const int*)d_in[4];
    const int*   etype = (const int*)d_in[5];
    const int*   eidx  = (const int*)d_in[6];
    float* out = (float*)d_out;

    const size_t xout_bytes = (size_t)N_NODES * 64 * 2;        // 12.8 MB bf16
    const size_t b_bytes    = (size_t)N_NODES * KCAT * 2;      // 57.6 MB bf16

    if (ws_size >= xout_bytes + b_bytes) {
        bf16* xout = (bf16*)d_ws;
        bf16* B    = (bf16*)((char*)d_ws + xout_bytes);
        // scratch in d_out (17.6 MB < 25.6 MB); final_gemm fully overwrites
        // d_out at the end of every call.
        u64* pay      = (u64*)d_out;            // 12.8 MB
        int* cnt      = (int*)(pay + N_EDGES);  // 1.6 MB
        int* offs     = cnt + NK;               // 1.6 MB
        int* partials = offs + NK;              // 2 KB (pad 512)
        u8*  rank     = (u8*)(partials + 512);  // 1.6 MB

        zero_buf<<<400, 256, 0, stream>>>((float4*)cnt, (long)(NK / 4));
        node_xform_g<<<(N_NODES + 63) / 64, 256, 0, stream>>>(nf, Wn, ntype, xout);
        count_rank<<<(N_EDGES / 4 + 255) / 256, 256, 0, stream>>>(eidx, etype, cnt, rank);
        scan_a<<<NBCHUNK, 256, 0, stream>>>(cnt, partials);
        scan_b<<<1, 512, 0, stream>>>(partials);
        scan_c<<<NBCHUNK, 256, 0, stream>>>(cnt, partials, offs);
        place_pay<<<(N_EDGES / 4 + 255) / 256, 256, 0, stream>>>(eidx, etype, rank, offs, pay);
        aggregate_g<<<(N_NODES + 3) / 4, 256, 0, stream>>>(pay, offs, xout, ef, B);
        final_gemm<<<(N_NODES + 63) / 64, 256, 0, stream>>>(B, Wm, out);
    } else {
        zero_buf<<<2048, 256, 0, stream>>>((float4*)d_out, (long)((size_t)out_size * 4 / 16));
        fallback_edge<<<4096, 256, 0, stream>>>(nf, ef, Wn, Wm, ntype, etype, eidx, out);
    }
}

// Round 12
// 326.324 us; speedup vs baseline: 1.1060x; 1.1060x over previous
//
#include <hip/hip_runtime.h>
#include <hip/hip_bf16.h>

#define N_NODES 100000
#define N_EDGES 1600000
#define D_IN 64
#define D_OUT 64
#define E_DIM 32
#define KCAT 288            // 3*64 (S buckets) + 3*32 (T buckets)
#define NK (4 * N_NODES)    // sort keys: 4*dst + etype (slot 3 unused -> count 0)
#define NBCHUNK 391         // ceil(NK / 1024)

typedef unsigned long long u64;
typedef __hip_bfloat16 bf16;
typedef unsigned char u8;

__device__ __forceinline__ float bflo(unsigned u) {
    union { unsigned v; float f; } x; x.v = u << 16; return x.f;
}
__device__ __forceinline__ float bfhi(unsigned u) {
    union { unsigned v; float f; } x; x.v = u & 0xffff0000u; return x.f;
}
__device__ __forceinline__ unsigned packbf2(float a, float b) {
    union { bf16 h[2]; unsigned u; } w;
    w.h[0] = __float2bfloat16(a); w.h[1] = __float2bfloat16(b);
    return w.u;
}

// ---------------------------------------------------------------------------
// zero helper (capture-safe)
// ---------------------------------------------------------------------------
__global__ __launch_bounds__(256) void zero_buf(float4* __restrict__ p, long n4) {
    long i = (long)blockIdx.x * 256 + threadIdx.x;
    long stride = (long)gridDim.x * 256;
    float4 z = make_float4(0.f, 0.f, 0.f, 0.f);
    for (; i < n4; i += stride) p[i] = z;
}

// ---------------------------------------------------------------------------
// node_xform_g: GEMM-style microtile (64 nodes x 64 cols / block).
// ---------------------------------------------------------------------------
__global__ __launch_bounds__(256) void node_xform_g(const float* __restrict__ nf,
                                                    const float* __restrict__ Wn,
                                                    const int* __restrict__ ntype,
                                                    bf16* __restrict__ xout) {
    __shared__ float Ws[2 * 64 * 64];   // [t][k][j], 32 KB
    __shared__ float As[64][65];        // [row][k], padded
    int tid = threadIdx.x;
    int n0 = blockIdx.x * 64;
    for (int i = tid; i < 2 * 64 * 64; i += 256) Ws[i] = Wn[i];
#pragma unroll
    for (int i = 0; i < 4; ++i) {
        int f = (i * 256 + tid) * 4;
        int r = f >> 6, c = f & 63;
        int n = n0 + r;
        float4 v = (n < N_NODES) ? *(const float4*)&nf[(size_t)n * 64 + c]
                                 : make_float4(0.f, 0.f, 0.f, 0.f);
        As[r][c + 0] = v.x; As[r][c + 1] = v.y; As[r][c + 2] = v.z; As[r][c + 3] = v.w;
    }
    __syncthreads();
    int tx = tid & 15, ty = tid >> 4;
    int r0 = n0 + ty * 4;
    int t0 = (r0 + 0 < N_NODES) ? ntype[r0 + 0] : 0;
    int t1 = (r0 + 1 < N_NODES) ? ntype[r0 + 1] : 0;
    int t2 = (r0 + 2 < N_NODES) ? ntype[r0 + 2] : 0;
    int t3 = (r0 + 3 < N_NODES) ? ntype[r0 + 3] : 0;
    float4 acc0 = {0,0,0,0}, acc1 = {0,0,0,0}, acc2 = {0,0,0,0}, acc3 = {0,0,0,0};
#pragma unroll 8
    for (int k = 0; k < 64; ++k) {
        float4 w0 = *(const float4*)&Ws[k * 64 + tx * 4];
        float4 w1 = *(const float4*)&Ws[4096 + k * 64 + tx * 4];
        float a0 = As[ty * 4 + 0][k];
        float a1 = As[ty * 4 + 1][k];
        float a2 = As[ty * 4 + 2][k];
        float a3 = As[ty * 4 + 3][k];
        float4 wa = t0 ? w1 : w0;
        float4 wb = t1 ? w1 : w0;
        float4 wc = t2 ? w1 : w0;
        float4 wd = t3 ? w1 : w0;
        acc0.x = fmaf(a0, wa.x, acc0.x); acc0.y = fmaf(a0, wa.y, acc0.y);
        acc0.z = fmaf(a0, wa.z, acc0.z); acc0.w = fmaf(a0, wa.w, acc0.w);
        acc1.x = fmaf(a1, wb.x, acc1.x); acc1.y = fmaf(a1, wb.y, acc1.y);
        acc1.z = fmaf(a1, wb.z, acc1.z); acc1.w = fmaf(a1, wb.w, acc1.w);
        acc2.x = fmaf(a2, wc.x, acc2.x); acc2.y = fmaf(a2, wc.y, acc2.y);
        acc2.z = fmaf(a2, wc.z, acc2.z); acc2.w = fmaf(a2, wc.w, acc2.w);
        acc3.x = fmaf(a3, wd.x, acc3.x); acc3.y = fmaf(a3, wd.y, acc3.y);
        acc3.z = fmaf(a3, wd.z, acc3.z); acc3.w = fmaf(a3, wd.w, acc3.w);
    }
#pragma unroll
    for (int r = 0; r < 4; ++r) {
        int n = r0 + r;
        if (n < N_NODES) {
            float4 a = (r == 0) ? acc0 : (r == 1) ? acc1 : (r == 2) ? acc2 : acc3;
            union { bf16 h[4]; uint2 u; } pk;
            pk.h[0] = __float2bfloat16(a.x); pk.h[1] = __float2bfloat16(a.y);
            pk.h[2] = __float2bfloat16(a.z); pk.h[3] = __float2bfloat16(a.w);
            *(uint2*)&xout[(size_t)n * 64 + tx * 4] = pk.u;
        }
    }
}

// ---------------------------------------------------------------------------
// count + rank: rank[i] = arrival order within key (4*dst+etype).
// ---------------------------------------------------------------------------
__global__ __launch_bounds__(256) void count_rank(const int* __restrict__ eidx,
                                                  const int* __restrict__ etype,
                                                  int* __restrict__ cnt,
                                                  u8* __restrict__ rank) {
    int i = blockIdx.x * 256 + threadIdx.x;   // edge quad id
    if (i >= N_EDGES / 4) return;
    int4 d = ((const int4*)(eidx + N_EDGES))[i];
    int4 t = ((const int4*)etype)[i];
    int r0 = atomicAdd(&cnt[4 * d.x + t.x], 1);
    int r1 = atomicAdd(&cnt[4 * d.y + t.y], 1);
    int r2 = atomicAdd(&cnt[4 * d.z + t.z], 1);
    int r3 = atomicAdd(&cnt[4 * d.w + t.w], 1);
    ((uchar4*)rank)[i] = make_uchar4((u8)r0, (u8)r1, (u8)r2, (u8)r3);
}

__global__ __launch_bounds__(256) void scan_a(const int* __restrict__ cnt,
                                              int* __restrict__ partials) {
    __shared__ int ws[4];
    int b = blockIdx.x, tid = threadIdx.x, lane = tid & 63, wid = tid >> 6;
    int i0 = b * 1024 + tid * 4;
    int s = 0;
#pragma unroll
    for (int k = 0; k < 4; ++k) { int i = i0 + k; if (i < NK) s += cnt[i]; }
#pragma unroll
    for (int d = 32; d > 0; d >>= 1) s += __shfl_down(s, d);
    if (lane == 0) ws[wid] = s;
    __syncthreads();
    if (tid == 0) partials[b] = ws[0] + ws[1] + ws[2] + ws[3];
}

__global__ __launch_bounds__(512) void scan_b(int* __restrict__ partials) {
    __shared__ int s[512];
    int tid = threadIdx.x;
    int v = (tid < NBCHUNK) ? partials[tid] : 0;
    s[tid] = v;
    __syncthreads();
    for (int d = 1; d < 512; d <<= 1) {
        int u = (tid >= d) ? s[tid - d] : 0;
        __syncthreads();
        s[tid] += u;
        __syncthreads();
    }
    if (tid < NBCHUNK) partials[tid] = s[tid] - v;   // exclusive
}

__global__ __launch_bounds__(256) void scan_c(const int* __restrict__ cnt,
                                              const int* __restrict__ partials,
                                              int* __restrict__ offs) {
    __shared__ int wsum[4];
    int b = blockIdx.x, tid = threadIdx.x, lane = tid & 63, wid = tid >> 6;
    int i0 = b * 1024 + tid * 4;
    int c0 = (i0 + 0 < NK) ? cnt[i0 + 0] : 0;
    int c1 = (i0 + 1 < NK) ? cnt[i0 + 1] : 0;
    int c2 = (i0 + 2 < NK) ? cnt[i0 + 2] : 0;
    int c3 = (i0 + 3 < NK) ? cnt[i0 + 3] : 0;
    int lsum = c0 + c1 + c2 + c3;
    int v = lsum;
#pragma unroll
    for (int d = 1; d < 64; d <<= 1) {
        int u = __shfl_up(v, d);
        if (lane >= d) v += u;
    }
    int wexcl = v - lsum;
    if (lane == 63) wsum[wid] = v;
    __syncthreads();
    int bexcl = 0;
    for (int w = 0; w < wid; ++w) bexcl += wsum[w];
    int base = partials[b] + bexcl + wexcl;
    if (i0 + 0 < NK) offs[i0 + 0] = base; base += c0;
    if (i0 + 1 < NK) offs[i0 + 1] = base; base += c1;
    if (i0 + 2 < NK) offs[i0 + 2] = base; base += c2;
    if (i0 + 3 < NK) offs[i0 + 3] = base;
}

// ---------------------------------------------------------------------------
// place_pay: 8B payload scatter (pos = offs[key]+rank, no atomics),
// one edge per thread (max MLP; x4 vectorization regressed in round 11).
// ---------------------------------------------------------------------------
__global__ __launch_bounds__(256) void place_pay(const int* __restrict__ eidx,
                                                 const int* __restrict__ etype,
                                                 const u8* __restrict__ rank,
                                                 const int* __restrict__ offs,
                                                 u64* __restrict__ pay) {
    int i = blockIdx.x * 256 + threadIdx.x;
    if (i >= N_EDGES) return;
    int d = eidx[N_EDGES + i];
    int s = eidx[i];
    int t = etype[i];
    int pos = offs[4 * d + t] + (int)rank[i];
    pay[pos] = (u64)(unsigned)s | ((u64)(unsigned)i << 32);
}

// ---------------------------------------------------------------------------
// aggregate_g: wave/node, PAIRED loads (2 rows per wave-load):
//   lane = cols (2c,2c+1) of row (j+2q+half), half = lane>>5, c = lane&31.
//   Per 8 edges: 4 uint xout loads + 4 dword ef loads (all hoisted),
//   readlane+cndmask addressing (no bpermute). Pair classification is
//   SCALAR (uniform branch, 3 adds) except boundary pairs (short
//   predicated path, ~2 per node). Fold halves at the end. Zero atomics.
// ---------------------------------------------------------------------------
__global__ __launch_bounds__(256) void aggregate_g(const u64* __restrict__ pay,
                                                   const int* __restrict__ offs,
                                                   const bf16* __restrict__ xout,
                                                   const float* __restrict__ ef,
                                                   bf16* __restrict__ B) {
    int wid = threadIdx.x >> 6, lane = threadIdx.x & 63;
    int n = blockIdx.x * 4 + wid;
    if (n >= N_NODES) return;
    int4 o = ((const int4*)offs)[n];           // starts t0,t1,t2, end
    int beg = __builtin_amdgcn_readfirstlane(o.x);
    int y   = __builtin_amdgcn_readfirstlane(o.y);
    int z   = __builtin_amdgcn_readfirstlane(o.z);
    int end = __builtin_amdgcn_readfirstlane(o.w);
    int c = lane & 31, half = lane >> 5;
    float xa0 = 0.f, xa1 = 0.f, xb0 = 0.f, xb1 = 0.f, xc0 = 0.f, xc1 = 0.f;
    float ea = 0.f, eb = 0.f, ec = 0.f;
    const unsigned short* xo = (const unsigned short*)xout;

    for (int base = beg; base < end; base += 64) {
        int m = end - base; if (m > 64) m = 64;
        u64 p = (lane < m) ? pay[base + lane] : 0ull;
        int plo = (int)(unsigned)p;            // src
        int phi = (int)(unsigned)(p >> 32);    // edge id
        for (int j = 0; j < m; j += 8) {
            // ---- hoisted addressing + loads for 4 pairs (8 edges) ----
            int sg0, sg1, sg2, sg3, eg0, eg1, eg2, eg3;
            {
                int a, b2;
                a = __builtin_amdgcn_readlane(plo, j + 0); b2 = __builtin_amdgcn_readlane(plo, j + 1); sg0 = half ? b2 : a;
                a = __builtin_amdgcn_readlane(plo, j + 2); b2 = __builtin_amdgcn_readlane(plo, j + 3); sg1 = half ? b2 : a;
                a = __builtin_amdgcn_readlane(plo, j + 4); b2 = __builtin_amdgcn_readlane(plo, j + 5); sg2 = half ? b2 : a;
                a = __builtin_amdgcn_readlane(plo, j + 6); b2 = __builtin_amdgcn_readlane(plo, j + 7); sg3 = half ? b2 : a;
                a = __builtin_amdgcn_readlane(phi, j + 0); b2 = __builtin_amdgcn_readlane(phi, j + 1); eg0 = half ? b2 : a;
                a = __builtin_amdgcn_readlane(phi, j + 2); b2 = __builtin_amdgcn_readlane(phi, j + 3); eg1 = half ? b2 : a;
                a = __builtin_amdgcn_readlane(phi, j + 4); b2 = __builtin_amdgcn_readlane(phi, j + 5); eg2 = half ? b2 : a;
                a = __builtin_amdgcn_readlane(phi, j + 6); b2 = __builtin_amdgcn_readlane(phi, j + 7); eg3 = half ? b2 : a;
            }
            unsigned xv0 = *(const unsigned*)(xo + (size_t)sg0 * 64 + c * 2);
            unsigned xv1 = *(const unsigned*)(xo + (size_t)sg1 * 64 + c * 2);
            unsigned xv2 = *(const unsigned*)(xo + (size_t)sg2 * 64 + c * 2);
            unsigned xv3 = *(const unsigned*)(xo + (size_t)sg3 * 64 + c * 2);
            float ev0 = ef[(size_t)eg0 * 32 + c];
            float ev1 = ef[(size_t)eg1 * 32 + c];
            float ev2 = ef[(size_t)eg2 * 32 + c];
            float ev3 = ef[(size_t)eg3 * 32 + c];
            // ---- accumulate 4 pairs ----
#pragma unroll
            for (int q = 0; q < 4; ++q) {
                unsigned xv = (q == 0) ? xv0 : (q == 1) ? xv1 : (q == 2) ? xv2 : xv3;
                float    ev = (q == 0) ? ev0 : (q == 1) ? ev1 : (q == 2) ? ev2 : ev3;
                float xl = bflo(xv), xh = bfhi(xv);
                int i0 = base + j + 2 * q;     // scalar
                if (i0 + 1 < y) {                                   // pair in seg0
                    xa0 += xl; xa1 += xh; ea += ev;
                } else if (i0 >= y && i0 + 1 < z) {                 // pair in seg1
                    xb0 += xl; xb1 += xh; eb += ev;
                } else if (i0 >= z && i0 + 1 < end) {               // pair in seg2
                    xc0 += xl; xc1 += xh; ec += ev;
                } else {                                            // boundary / tail
                    int idx = i0 + half;
                    bool v = idx < end;
                    float fl = v ? xl : 0.f, fh = v ? xh : 0.f, fe = v ? ev : 0.f;
                    if (idx < y)      { xa0 += fl; xa1 += fh; ea += fe; }
                    else if (idx < z) { xb0 += fl; xb1 += fh; eb += fe; }
                    else              { xc0 += fl; xc1 += fh; ec += fe; }
                }
            }
        }
    }
    // fold the two halves (rows were split across lane<32 / lane>=32)
    xa0 += __shfl_down(xa0, 32); xa1 += __shfl_down(xa1, 32);
    xb0 += __shfl_down(xb0, 32); xb1 += __shfl_down(xb1, 32);
    xc0 += __shfl_down(xc0, 32); xc1 += __shfl_down(xc1, 32);
    ea  += __shfl_down(ea, 32);  eb  += __shfl_down(eb, 32);  ec += __shfl_down(ec, 32);

    if (lane < 32) {
        bf16* Bn = B + (size_t)n * KCAT;
        *(unsigned*)&Bn[2 * c]       = packbf2(xa0, xa1);
        *(unsigned*)&Bn[64 + 2 * c]  = packbf2(xb0, xb1);
        *(unsigned*)&Bn[128 + 2 * c] = packbf2(xc0, xc1);
        Bn[192 + c] = __float2bfloat16(ea);
        Bn[224 + c] = __float2bfloat16(eb);
        Bn[256 + c] = __float2bfloat16(ec);
    }
}

// ---------------------------------------------------------------------------
// K3: out = B(bf16) @ Wcat(fp32), Wcat[288][64] remapped from W_msg on load.
// ---------------------------------------------------------------------------
__global__ __launch_bounds__(256) void final_gemm(const bf16* __restrict__ B,
                                                  const float* __restrict__ Wm,
                                                  float* __restrict__ out) {
    __shared__ float As[64][33];   // +1 pad
    __shared__ float Ws[32][64];
    int tid = threadIdx.x;
    int n0 = blockIdx.x * 64;
    int tx = tid & 15;
    int ty = tid >> 4;
    float acc[4][4] = {};

    for (int k0 = 0; k0 < KCAT; k0 += 32) {
#pragma unroll
        for (int i = 0; i < 8; ++i) {
            int f = i * 256 + tid;
            int r = f >> 5, cc = f & 31;
            int n = n0 + r;
            As[r][cc] = (n < N_NODES) ? __bfloat162float(B[(size_t)n * KCAT + k0 + cc]) : 0.f;
        }
#pragma unroll
        for (int i = 0; i < 8; ++i) {
            int f = i * 256 + tid;
            int kk = f >> 6, j = f & 63;
            int r = k0 + kk;
            int t, kin;
            if (r < 192) { t = r >> 6; kin = r & 63; }
            else         { int q = r - 192; t = q >> 5; kin = 64 + (q & 31); }
            Ws[kk][j] = Wm[(t * 96 + kin) * 64 + j];
        }
        __syncthreads();
#pragma unroll
        for (int kk = 0; kk < 32; ++kk) {
            float a0 = As[ty * 4 + 0][kk];
            float a1 = As[ty * 4 + 1][kk];
            float a2 = As[ty * 4 + 2][kk];
            float a3 = As[ty * 4 + 3][kk];
            float4 w = *(const float4*)&Ws[kk][tx * 4];
            acc[0][0] = fmaf(a0, w.x, acc[0][0]); acc[0][1] = fmaf(a0, w.y, acc[0][1]);
            acc[0][2] = fmaf(a0, w.z, acc[0][2]); acc[0][3] = fmaf(a0, w.w, acc[0][3]);
            acc[1][0] = fmaf(a1, w.x, acc[1][0]); acc[1][1] = fmaf(a1, w.y, acc[1][1]);
            acc[1][2] = fmaf(a1, w.z, acc[1][2]); acc[1][3] = fmaf(a1, w.w, acc[1][3]);
            acc[2][0] = fmaf(a2, w.x, acc[2][0]); acc[2][1] = fmaf(a2, w.y, acc[2][1]);
            acc[2][2] = fmaf(a2, w.z, acc[2][2]); acc[2][3] = fmaf(a2, w.w, acc[2][3]);
            acc[3][0] = fmaf(a3, w.x, acc[3][0]); acc[3][1] = fmaf(a3, w.y, acc[3][1]);
            acc[3][2] = fmaf(a3, w.z, acc[3][2]); acc[3][3] = fmaf(a3, w.w, acc[3][3]);
        }
        __syncthreads();
    }
#pragma unroll
    for (int r = 0; r < 4; ++r) {
        int n = n0 + ty * 4 + r;
        if (n < N_NODES) {
            float4 v = make_float4(acc[r][0], acc[r][1], acc[r][2], acc[r][3]);
            *(float4*)&out[(size_t)n * 64 + tx * 4] = v;
        }
    }
}

// ---------------------------------------------------------------------------
// Fallback (ws tiny): direct wave-per-edge, fp32.
// ---------------------------------------------------------------------------
__global__ __launch_bounds__(256) void fallback_edge(const float* __restrict__ nf,
                                                     const float* __restrict__ ef,
                                                     const float* __restrict__ Wn,
                                                     const float* __restrict__ Wm,
                                                     const int* __restrict__ ntype,
                                                     const int* __restrict__ etype,
                                                     const int* __restrict__ eidx,
                                                     float* __restrict__ out) {
    __shared__ float wn[2 * 64 * 64];
    __shared__ float wm[3 * 96 * 64];
    for (int i = threadIdx.x; i < 2 * 64 * 64; i += 256) wn[i] = Wn[i];
    for (int i = threadIdx.x; i < 3 * 96 * 64; i += 256) wm[i] = Wm[i];
    __syncthreads();
    int wid = threadIdx.x >> 6, lane = threadIdx.x & 63;
    for (int e = blockIdx.x * 4 + wid; e < N_EDGES; e += gridDim.x * 4) {
        int t = etype[e];
        int s = eidx[e];
        int d = eidx[N_EDGES + e];
        int nt = ntype[s];
        float xs = nf[(long)s * 64 + lane];
        const float* wcol = &wn[nt * 4096 + lane];
        float xo = 0.f;
#pragma unroll 16
        for (int k = 0; k < 64; ++k) xo = fmaf(__shfl(xs, k), wcol[k * 64], xo);
        float ev = ef[(long)e * 32 + (lane & 31)];
        const float* mcol = &wm[t * 96 * 64 + lane];
        float m = 0.f;
#pragma unroll 16
        for (int k = 0; k < 64; ++k) m = fmaf(__shfl(xo, k), mcol[k * 64], m);
#pragma unroll 8
        for (int k = 0; k < 32; ++k) m = fmaf(__shfl(ev, k), mcol[(64 + k) * 64], m);
        atomicAdd(&out[(long)d * 64 + lane], m);
    }
}

// ---------------------------------------------------------------------------
extern "C" void kernel_launch(void* const* d_in, const int* in_sizes, int n_in,
                              void* d_out, int out_size, void* d_ws, size_t ws_size,
                              hipStream_t stream) {
    const float* nf    = (const float*)d_in[0];
    const float* ef    = (const float*)d_in[1];
    const float* Wn    = (const float*)d_in[2];
    const float* Wm    = (const float*)d_in[3];
    const int*   ntype = (const int*)d_in[4];
    const int*   etype = (const int*)d_in[5];
    const int*   eidx  = (const int*)d_in[6];
    float* out = (float*)d_out;

    const size_t xout_bytes = (size_t)N_NODES * 64 * 2;        // 12.8 MB bf16
    const size_t b_bytes    = (size_t)N_NODES * KCAT * 2;      // 57.6 MB bf16

    if (ws_size >= xout_bytes + b_bytes) {
        bf16* xout = (bf16*)d_ws;
        bf16* B    = (bf16*)((char*)d_ws + xout_bytes);
        // scratch in d_out (17.6 MB < 25.6 MB); final_gemm fully overwrites
        // d_out at the end of every call.
        u64* pay      = (u64*)d_out;            // 12.8 MB
        int* cnt      = (int*)(pay + N_EDGES);  // 1.6 MB
        int* offs     = cnt + NK;               // 1.6 MB
        int* partials = offs + NK;              // 2 KB (pad 512)
        u8*  rank     = (u8*)(partials + 512);  // 1.6 MB

        zero_buf<<<400, 256, 0, stream>>>((float4*)cnt, (long)(NK / 4));
        node_xform_g<<<(N_NODES + 63) / 64, 256, 0, stream>>>(nf, Wn, ntype, xout);
        count_rank<<<(N_EDGES / 4 + 255) / 256, 256, 0, stream>>>(eidx, etype, cnt, rank);
        scan_a<<<NBCHUNK, 256, 0, stream>>>(cnt, partials);
        scan_b<<<1, 512, 0, stream>>>(partials);
        scan_c<<<NBCHUNK, 256, 0, stream>>>(cnt, partials, offs);
        place_pay<<<(N_EDGES + 255) / 256, 256, 0, stream>>>(eidx, etype, rank, offs, pay);
        aggregate_g<<<(N_NODES + 3) / 4, 256, 0, stream>>>(pay, offs, xout, ef, B);
        final_gemm<<<(N_NODES + 63) / 64, 256, 0, stream>>>(B, Wm, out);
    } else {
        zero_buf<<<2048, 256, 0, stream>>>((float4*)d_out, (long)((size_t)out_size * 4 / 16));
        fallback_edge<<<4096, 256, 0, stream>>>(nf, ef, Wn, Wm, ntype, etype, eidx, out);
    }
}

// Round 13
// 310.587 us; speedup vs baseline: 1.1621x; 1.0507x over previous
//
#include <hip/hip_runtime.h>
#include <hip/hip_bf16.h>

#define N_NODES 100000
#define N_EDGES 1600000
#define D_IN 64
#define D_OUT 64
#define E_DIM 32
#define KCAT 288            // 3*64 (S buckets) + 3*32 (T buckets)
#define NK (4 * N_NODES)    // sort keys: 4*dst + etype (slot 3 unused -> count 0)
#define NBCHUNK 391         // ceil(NK / 1024)

typedef unsigned long long u64;
typedef __hip_bfloat16 bf16;
typedef unsigned char u8;

__device__ __forceinline__ float bflo(unsigned u) {
    union { unsigned v; float f; } x; x.v = u << 16; return x.f;
}
__device__ __forceinline__ float bfhi(unsigned u) {
    union { unsigned v; float f; } x; x.v = u & 0xffff0000u; return x.f;
}
__device__ __forceinline__ unsigned packbf2(float a, float b) {
    union { bf16 h[2]; unsigned u; } w;
    w.h[0] = __float2bfloat16(a); w.h[1] = __float2bfloat16(b);
    return w.u;
}

// ---------------------------------------------------------------------------
// zero helper (capture-safe)
// ---------------------------------------------------------------------------
__global__ __launch_bounds__(256) void zero_buf(float4* __restrict__ p, long n4) {
    long i = (long)blockIdx.x * 256 + threadIdx.x;
    long stride = (long)gridDim.x * 256;
    float4 z = make_float4(0.f, 0.f, 0.f, 0.f);
    for (; i < n4; i += stride) p[i] = z;
}

// ---------------------------------------------------------------------------
// node_xform_g: GEMM-style microtile (64 nodes x 64 cols / block).
// ---------------------------------------------------------------------------
__global__ __launch_bounds__(256) void node_xform_g(const float* __restrict__ nf,
                                                    const float* __restrict__ Wn,
                                                    const int* __restrict__ ntype,
                                                    bf16* __restrict__ xout) {
    __shared__ float Ws[2 * 64 * 64];   // [t][k][j], 32 KB
    __shared__ float As[64][65];        // [row][k], padded
    int tid = threadIdx.x;
    int n0 = blockIdx.x * 64;
    for (int i = tid; i < 2 * 64 * 64; i += 256) Ws[i] = Wn[i];
#pragma unroll
    for (int i = 0; i < 4; ++i) {
        int f = (i * 256 + tid) * 4;
        int r = f >> 6, c = f & 63;
        int n = n0 + r;
        float4 v = (n < N_NODES) ? *(const float4*)&nf[(size_t)n * 64 + c]
                                 : make_float4(0.f, 0.f, 0.f, 0.f);
        As[r][c + 0] = v.x; As[r][c + 1] = v.y; As[r][c + 2] = v.z; As[r][c + 3] = v.w;
    }
    __syncthreads();
    int tx = tid & 15, ty = tid >> 4;
    int r0 = n0 + ty * 4;
    int t0 = (r0 + 0 < N_NODES) ? ntype[r0 + 0] : 0;
    int t1 = (r0 + 1 < N_NODES) ? ntype[r0 + 1] : 0;
    int t2 = (r0 + 2 < N_NODES) ? ntype[r0 + 2] : 0;
    int t3 = (r0 + 3 < N_NODES) ? ntype[r0 + 3] : 0;
    float4 acc0 = {0,0,0,0}, acc1 = {0,0,0,0}, acc2 = {0,0,0,0}, acc3 = {0,0,0,0};
#pragma unroll 8
    for (int k = 0; k < 64; ++k) {
        float4 w0 = *(const float4*)&Ws[k * 64 + tx * 4];
        float4 w1 = *(const float4*)&Ws[4096 + k * 64 + tx * 4];
        float a0 = As[ty * 4 + 0][k];
        float a1 = As[ty * 4 + 1][k];
        float a2 = As[ty * 4 + 2][k];
        float a3 = As[ty * 4 + 3][k];
        float4 wa = t0 ? w1 : w0;
        float4 wb = t1 ? w1 : w0;
        float4 wc = t2 ? w1 : w0;
        float4 wd = t3 ? w1 : w0;
        acc0.x = fmaf(a0, wa.x, acc0.x); acc0.y = fmaf(a0, wa.y, acc0.y);
        acc0.z = fmaf(a0, wa.z, acc0.z); acc0.w = fmaf(a0, wa.w, acc0.w);
        acc1.x = fmaf(a1, wb.x, acc1.x); acc1.y = fmaf(a1, wb.y, acc1.y);
        acc1.z = fmaf(a1, wb.z, acc1.z); acc1.w = fmaf(a1, wb.w, acc1.w);
        acc2.x = fmaf(a2, wc.x, acc2.x); acc2.y = fmaf(a2, wc.y, acc2.y);
        acc2.z = fmaf(a2, wc.z, acc2.z); acc2.w = fmaf(a2, wc.w, acc2.w);
        acc3.x = fmaf(a3, wd.x, acc3.x); acc3.y = fmaf(a3, wd.y, acc3.y);
        acc3.z = fmaf(a3, wd.z, acc3.z); acc3.w = fmaf(a3, wd.w, acc3.w);
    }
#pragma unroll
    for (int r = 0; r < 4; ++r) {
        int n = r0 + r;
        if (n < N_NODES) {
            float4 a = (r == 0) ? acc0 : (r == 1) ? acc1 : (r == 2) ? acc2 : acc3;
            union { bf16 h[4]; uint2 u; } pk;
            pk.h[0] = __float2bfloat16(a.x); pk.h[1] = __float2bfloat16(a.y);
            pk.h[2] = __float2bfloat16(a.z); pk.h[3] = __float2bfloat16(a.w);
            *(uint2*)&xout[(size_t)n * 64 + tx * 4] = pk.u;
        }
    }
}

// ---------------------------------------------------------------------------
// count + rank: rank[i] = arrival order within key (4*dst+etype).
// ---------------------------------------------------------------------------
__global__ __launch_bounds__(256) void count_rank(const int* __restrict__ eidx,
                                                  const int* __restrict__ etype,
                                                  int* __restrict__ cnt,
                                                  u8* __restrict__ rank) {
    int i = blockIdx.x * 256 + threadIdx.x;   // edge quad id
    if (i >= N_EDGES / 4) return;
    int4 d = ((const int4*)(eidx + N_EDGES))[i];
    int4 t = ((const int4*)etype)[i];
    int r0 = atomicAdd(&cnt[4 * d.x + t.x], 1);
    int r1 = atomicAdd(&cnt[4 * d.y + t.y], 1);
    int r2 = atomicAdd(&cnt[4 * d.z + t.z], 1);
    int r3 = atomicAdd(&cnt[4 * d.w + t.w], 1);
    ((uchar4*)rank)[i] = make_uchar4((u8)r0, (u8)r1, (u8)r2, (u8)r3);
}

__global__ __launch_bounds__(256) void scan_a(const int* __restrict__ cnt,
                                              int* __restrict__ partials) {
    __shared__ int ws[4];
    int b = blockIdx.x, tid = threadIdx.x, lane = tid & 63, wid = tid >> 6;
    int i0 = b * 1024 + tid * 4;
    int s = 0;
#pragma unroll
    for (int k = 0; k < 4; ++k) { int i = i0 + k; if (i < NK) s += cnt[i]; }
#pragma unroll
    for (int d = 32; d > 0; d >>= 1) s += __shfl_down(s, d);
    if (lane == 0) ws[wid] = s;
    __syncthreads();
    if (tid == 0) partials[b] = ws[0] + ws[1] + ws[2] + ws[3];
}

__global__ __launch_bounds__(512) void scan_b(int* __restrict__ partials) {
    __shared__ int s[512];
    int tid = threadIdx.x;
    int v = (tid < NBCHUNK) ? partials[tid] : 0;
    s[tid] = v;
    __syncthreads();
    for (int d = 1; d < 512; d <<= 1) {
        int u = (tid >= d) ? s[tid - d] : 0;
        __syncthreads();
        s[tid] += u;
        __syncthreads();
    }
    if (tid < NBCHUNK) partials[tid] = s[tid] - v;   // exclusive
}

__global__ __launch_bounds__(256) void scan_c(const int* __restrict__ cnt,
                                              const int* __restrict__ partials,
                                              int* __restrict__ offs) {
    __shared__ int wsum[4];
    int b = blockIdx.x, tid = threadIdx.x, lane = tid & 63, wid = tid >> 6;
    int i0 = b * 1024 + tid * 4;
    int c0 = (i0 + 0 < NK) ? cnt[i0 + 0] : 0;
    int c1 = (i0 + 1 < NK) ? cnt[i0 + 1] : 0;
    int c2 = (i0 + 2 < NK) ? cnt[i0 + 2] : 0;
    int c3 = (i0 + 3 < NK) ? cnt[i0 + 3] : 0;
    int lsum = c0 + c1 + c2 + c3;
    int v = lsum;
#pragma unroll
    for (int d = 1; d < 64; d <<= 1) {
        int u = __shfl_up(v, d);
        if (lane >= d) v += u;
    }
    int wexcl = v - lsum;
    if (lane == 63) wsum[wid] = v;
    __syncthreads();
    int bexcl = 0;
    for (int w = 0; w < wid; ++w) bexcl += wsum[w];
    int base = partials[b] + bexcl + wexcl;
    if (i0 + 0 < NK) offs[i0 + 0] = base; base += c0;
    if (i0 + 1 < NK) offs[i0 + 1] = base; base += c1;
    if (i0 + 2 < NK) offs[i0 + 2] = base; base += c2;
    if (i0 + 3 < NK) offs[i0 + 3] = base;
}

// ---------------------------------------------------------------------------
// place_pay: 8B payload scatter (pos = offs[key]+rank, no atomics),
// one edge per thread (max MLP).
// ---------------------------------------------------------------------------
__global__ __launch_bounds__(256) void place_pay(const int* __restrict__ eidx,
                                                 const int* __restrict__ etype,
                                                 const u8* __restrict__ rank,
                                                 const int* __restrict__ offs,
                                                 u64* __restrict__ pay) {
    int i = blockIdx.x * 256 + threadIdx.x;
    if (i >= N_EDGES) return;
    int d = eidx[N_EDGES + i];
    int s = eidx[i];
    int t = etype[i];
    int pos = offs[4 * d + t] + (int)rank[i];
    pay[pos] = (u64)(unsigned)s | ((u64)(unsigned)i << 32);
}

// ---------------------------------------------------------------------------
// aggregate_g: grid-strided wave/node, PAIRED loads (2 rows per wave-load),
// 16-edge inner step with ALL 8 xout + 8 ef loads hoisted (deep MLP).
// Next node's offs prefetched. Scalar pair classification. Zero atomics.
// ---------------------------------------------------------------------------
__global__ __launch_bounds__(256) void aggregate_g(const u64* __restrict__ pay,
                                                   const int* __restrict__ offs,
                                                   const bf16* __restrict__ xout,
                                                   const float* __restrict__ ef,
                                                   bf16* __restrict__ B) {
    int wid = threadIdx.x >> 6, lane = threadIdx.x & 63;
    int gw = blockIdx.x * 4 + wid, nw = gridDim.x * 4;
    int c = lane & 31, half = lane >> 5;
    const unsigned short* xo = (const unsigned short*)xout;
    if (gw >= N_NODES) return;

    int4 o = ((const int4*)offs)[gw];
    for (int n = gw; n < N_NODES; n += nw) {
        int nn = n + nw;
        int4 onext;
        if (nn < N_NODES) onext = ((const int4*)offs)[nn];   // prefetch
        int beg = __builtin_amdgcn_readfirstlane(o.x);
        int y   = __builtin_amdgcn_readfirstlane(o.y);
        int z   = __builtin_amdgcn_readfirstlane(o.z);
        int end = __builtin_amdgcn_readfirstlane(o.w);
        float xa0 = 0.f, xa1 = 0.f, xb0 = 0.f, xb1 = 0.f, xc0 = 0.f, xc1 = 0.f;
        float ea = 0.f, eb = 0.f, ec = 0.f;

        for (int base = beg; base < end; base += 64) {
            int m = end - base; if (m > 64) m = 64;
            u64 p = (lane < m) ? pay[base + lane] : 0ull;
            int plo = (int)(unsigned)p;            // src
            int phi = (int)(unsigned)(p >> 32);    // edge id
            for (int j = 0; j < m; j += 16) {
                int sgp[8], egp[8];
#pragma unroll
                for (int q = 0; q < 8; ++q) {
                    int a  = __builtin_amdgcn_readlane(plo, j + 2 * q);
                    int b2 = __builtin_amdgcn_readlane(plo, j + 2 * q + 1);
                    sgp[q] = half ? b2 : a;
                    a  = __builtin_amdgcn_readlane(phi, j + 2 * q);
                    b2 = __builtin_amdgcn_readlane(phi, j + 2 * q + 1);
                    egp[q] = half ? b2 : a;
                }
                unsigned xv[8];
                float evv[8];
#pragma unroll
                for (int q = 0; q < 8; ++q) {
                    xv[q]  = *(const unsigned*)(xo + (size_t)sgp[q] * 64 + c * 2);
                    evv[q] = ef[(size_t)egp[q] * 32 + c];
                }
#pragma unroll
                for (int q = 0; q < 8; ++q) {
                    float xl = bflo(xv[q]), xh = bfhi(xv[q]);
                    float ev = evv[q];
                    int i0 = base + j + 2 * q;     // scalar
                    if (i0 + 1 < y) {                                   // pair in seg0
                        xa0 += xl; xa1 += xh; ea += ev;
                    } else if (i0 >= y && i0 + 1 < z) {                 // pair in seg1
                        xb0 += xl; xb1 += xh; eb += ev;
                    } else if (i0 >= z && i0 + 1 < end) {               // pair in seg2
                        xc0 += xl; xc1 += xh; ec += ev;
                    } else {                                            // boundary / tail
                        int idx = i0 + half;
                        bool v = idx < end;
                        float fl = v ? xl : 0.f, fh = v ? xh : 0.f, fe = v ? ev : 0.f;
                        if (idx < y)      { xa0 += fl; xa1 += fh; ea += fe; }
                        else if (idx < z) { xb0 += fl; xb1 += fh; eb += fe; }
                        else              { xc0 += fl; xc1 += fh; ec += fe; }
                    }
                }
            }
        }
        // fold the two halves
        xa0 += __shfl_down(xa0, 32); xa1 += __shfl_down(xa1, 32);
        xb0 += __shfl_down(xb0, 32); xb1 += __shfl_down(xb1, 32);
        xc0 += __shfl_down(xc0, 32); xc1 += __shfl_down(xc1, 32);
        ea  += __shfl_down(ea, 32);  eb  += __shfl_down(eb, 32);  ec += __shfl_down(ec, 32);

        if (lane < 32) {
            bf16* Bn = B + (size_t)n * KCAT;
            *(unsigned*)&Bn[2 * c]       = packbf2(xa0, xa1);
            *(unsigned*)&Bn[64 + 2 * c]  = packbf2(xb0, xb1);
            *(unsigned*)&Bn[128 + 2 * c] = packbf2(xc0, xc1);
            Bn[192 + c] = __float2bfloat16(ea);
            Bn[224 + c] = __float2bfloat16(eb);
            Bn[256 + c] = __float2bfloat16(ec);
        }
        o = onext;
    }
}

// ---------------------------------------------------------------------------
// K3: out = B(bf16) @ Wcat(fp32), Wcat[288][64] remapped from W_msg on load.
// Vectorized B staging: one uint4 (8 bf16) per thread -> fp32 LDS.
// ---------------------------------------------------------------------------
__global__ __launch_bounds__(256) void final_gemm(const bf16* __restrict__ B,
                                                  const float* __restrict__ Wm,
                                                  float* __restrict__ out) {
    __shared__ float As[64][36];   // row stride 144B (16B-aligned, 2-way bank = free)
    __shared__ float Ws[32][64];
    int tid = threadIdx.x;
    int n0 = blockIdx.x * 64;
    int tx = tid & 15;
    int ty = tid >> 4;
    float acc[4][4] = {};

    for (int k0 = 0; k0 < KCAT; k0 += 32) {
        // stage A tile [64 nodes][32 k]: uint4 = 8 bf16 per thread
        {
            int r = tid >> 2, cb = (tid & 3) * 8;
            int n = n0 + r;
            uint4 v = make_uint4(0u, 0u, 0u, 0u);
            if (n < N_NODES) v = *(const uint4*)&B[(size_t)n * KCAT + k0 + cb];
            *(float4*)&As[r][cb]     = make_float4(bflo(v.x), bfhi(v.x), bflo(v.y), bfhi(v.y));
            *(float4*)&As[r][cb + 4] = make_float4(bflo(v.z), bfhi(v.z), bflo(v.w), bfhi(v.w));
        }
        // stage W tile [32 k][64 j] with Wcat remap, float4 per thread x2
#pragma unroll
        for (int i = 0; i < 2; ++i) {
            int f = (i * 256 + tid) * 4;
            int kk = f >> 6, j = f & 63;
            int r = k0 + kk;
            int t, kin;
            if (r < 192) { t = r >> 6; kin = r & 63; }
            else         { int q = r - 192; t = q >> 5; kin = 64 + (q & 31); }
            *(float4*)&Ws[kk][j] = *(const float4*)&Wm[(t * 96 + kin) * 64 + j];
        }
        __syncthreads();
#pragma unroll
        for (int kk = 0; kk < 32; ++kk) {
            float a0 = As[ty * 4 + 0][kk];
            float a1 = As[ty * 4 + 1][kk];
            float a2 = As[ty * 4 + 2][kk];
            float a3 = As[ty * 4 + 3][kk];
            float4 w = *(const float4*)&Ws[kk][tx * 4];
            acc[0][0] = fmaf(a0, w.x, acc[0][0]); acc[0][1] = fmaf(a0, w.y, acc[0][1]);
            acc[0][2] = fmaf(a0, w.z, acc[0][2]); acc[0][3] = fmaf(a0, w.w, acc[0][3]);
            acc[1][0] = fmaf(a1, w.x, acc[1][0]); acc[1][1] = fmaf(a1, w.y, acc[1][1]);
            acc[1][2] = fmaf(a1, w.z, acc[1][2]); acc[1][3] = fmaf(a1, w.w, acc[1][3]);
            acc[2][0] = fmaf(a2, w.x, acc[2][0]); acc[2][1] = fmaf(a2, w.y, acc[2][1]);
            acc[2][2] = fmaf(a2, w.z, acc[2][2]); acc[2][3] = fmaf(a2, w.w, acc[2][3]);
            acc[3][0] = fmaf(a3, w.x, acc[3][0]); acc[3][1] = fmaf(a3, w.y, acc[3][1]);
            acc[3][2] = fmaf(a3, w.z, acc[3][2]); acc[3][3] = fmaf(a3, w.w, acc[3][3]);
        }
        __syncthreads();
    }
#pragma unroll
    for (int r = 0; r < 4; ++r) {
        int n = n0 + ty * 4 + r;
        if (n < N_NODES) {
            float4 v = make_float4(acc[r][0], acc[r][1], acc[r][2], acc[r][3]);
            *(float4*)&out[(size_t)n * 64 + tx * 4] = v;
        }
    }
}

// ---------------------------------------------------------------------------
// Fallback (ws tiny): direct wave-per-edge, fp32.
// ---------------------------------------------------------------------------
__global__ __launch_bounds__(256) void fallback_edge(const float* __restrict__ nf,
                                                     const float* __restrict__ ef,
                                                     const float* __restrict__ Wn,
                                                     const float* __restrict__ Wm,
                                                     const int* __restrict__ ntype,
                                                     const int* __restrict__ etype,
                                                     const int* __restrict__ eidx,
                                                     float* __restrict__ out) {
    __shared__ float wn[2 * 64 * 64];
    __shared__ float wm[3 * 96 * 64];
    for (int i = threadIdx.x; i < 2 * 64 * 64; i += 256) wn[i] = Wn[i];
    for (int i = threadIdx.x; i < 3 * 96 * 64; i += 256) wm[i] = Wm[i];
    __syncthreads();
    int wid = threadIdx.x >> 6, lane = threadIdx.x & 63;
    for (int e = blockIdx.x * 4 + wid; e < N_EDGES; e += gridDim.x * 4) {
        int t = etype[e];
        int s = eidx[e];
        int d = eidx[N_EDGES + e];
        int nt = ntype[s];
        float xs = nf[(long)s * 64 + lane];
        const float* wcol = &wn[nt * 4096 + lane];
        float xo = 0.f;
#pragma unroll 16
        for (int k = 0; k < 64; ++k) xo = fmaf(__shfl(xs, k), wcol[k * 64], xo);
        float ev = ef[(long)e * 32 + (lane & 31)];
        const float* mcol = &wm[t * 96 * 64 + lane];
        float m = 0.f;
#pragma unroll 16
        for (int k = 0; k < 64; ++k) m = fmaf(__shfl(xo, k), mcol[k * 64], m);
#pragma unroll 8
        for (int k = 0; k < 32; ++k) m = fmaf(__shfl(ev, k), mcol[(64 + k) * 64], m);
        atomicAdd(&out[(long)d * 64 + lane], m);
    }
}

// ---------------------------------------------------------------------------
extern "C" void kernel_launch(void* const* d_in, const int* in_sizes, int n_in,
                              void* d_out, int out_size, void* d_ws, size_t ws_size,
                              hipStream_t stream) {
    const float* nf    = (const float*)d_in[0];
    const float* ef    = (const float*)d_in[1];
    const float* Wn    = (const float*)d_in[2];
    const float* Wm    = (const float*)d_in[3];
    const int*   ntype = (const int*)d_in[4];
    const int*   etype = (const int*)d_in[5];
    const int*   eidx  = (const int*)d_in[6];
    float* out = (float*)d_out;

    const size_t xout_bytes = (size_t)N_NODES * 64 * 2;        // 12.8 MB bf16
    const size_t b_bytes    = (size_t)N_NODES * KCAT * 2;      // 57.6 MB bf16

    if (ws_size >= xout_bytes + b_bytes) {
        bf16* xout = (bf16*)d_ws;
        bf16* B    = (bf16*)((char*)d_ws + xout_bytes);
        // scratch in d_out (17.6 MB < 25.6 MB); final_gemm fully overwrites
        // d_out at the end of every call.
        u64* pay      = (u64*)d_out;            // 12.8 MB
        int* cnt      = (int*)(pay + N_EDGES);  // 1.6 MB
        int* offs     = cnt + NK;               // 1.6 MB
        int* partials = offs + NK;              // 2 KB (pad 512)
        u8*  rank     = (u8*)(partials + 512);  // 1.6 MB

        zero_buf<<<400, 256, 0, stream>>>((float4*)cnt, (long)(NK / 4));
        node_xform_g<<<(N_NODES + 63) / 64, 256, 0, stream>>>(nf, Wn, ntype, xout);
        count_rank<<<(N_EDGES / 4 + 255) / 256, 256, 0, stream>>>(eidx, etype, cnt, rank);
        scan_a<<<NBCHUNK, 256, 0, stream>>>(cnt, partials);
        scan_b<<<1, 512, 0, stream>>>(partials);
        scan_c<<<NBCHUNK, 256, 0, stream>>>(cnt, partials, offs);
        place_pay<<<(N_EDGES + 255) / 256, 256, 0, stream>>>(eidx, etype, rank, offs, pay);
        aggregate_g<<<4096, 256, 0, stream>>>(pay, offs, xout, ef, B);
        final_gemm<<<(N_NODES + 63) / 64, 256, 0, stream>>>(B, Wm, out);
    } else {
        zero_buf<<<2048, 256, 0, stream>>>((float4*)d_out, (long)((size_t)out_size * 4 / 16));
        fallback_edge<<<4096, 256, 0, stream>>>(nf, ef, Wn, Wm, ntype, etype, eidx, out);
    }
}

// Round 14
// 307.820 us; speedup vs baseline: 1.1725x; 1.0090x over previous
//
#include <hip/hip_runtime.h>
#include <hip/hip_bf16.h>

#define N_NODES 100000
#define N_EDGES 1600000
#define D_IN 64
#define D_OUT 64
#define E_DIM 32
#define KCAT 288            // 3*64 (S buckets) + 3*32 (T buckets)
#define NK (4 * N_NODES)    // sort keys: 4*dst + etype (slot 3 unused -> count 0)
#define NBCHUNK 391         // ceil(NK / 1024)

typedef unsigned long long u64;
typedef __hip_bfloat16 bf16;
typedef unsigned char u8;

__device__ __forceinline__ float bflo(unsigned u) {
    union { unsigned v; float f; } x; x.v = u << 16; return x.f;
}
__device__ __forceinline__ float bfhi(unsigned u) {
    union { unsigned v; float f; } x; x.v = u & 0xffff0000u; return x.f;
}
__device__ __forceinline__ unsigned packbf2(float a, float b) {
    union { bf16 h[2]; unsigned u; } w;
    w.h[0] = __float2bfloat16(a); w.h[1] = __float2bfloat16(b);
    return w.u;
}

// ---------------------------------------------------------------------------
// zero helper (capture-safe) -- fallback path only
// ---------------------------------------------------------------------------
__global__ __launch_bounds__(256) void zero_buf(float4* __restrict__ p, long n4) {
    long i = (long)blockIdx.x * 256 + threadIdx.x;
    long stride = (long)gridDim.x * 256;
    float4 z = make_float4(0.f, 0.f, 0.f, 0.f);
    for (; i < n4; i += stride) p[i] = z;
}

// ---------------------------------------------------------------------------
// node_xform_g: GEMM-style microtile (64 nodes x 64 cols / block).
// Also zeroes cnt[] (fused; stream order guarantees it precedes count_rank).
// ---------------------------------------------------------------------------
__global__ __launch_bounds__(256) void node_xform_g(const float* __restrict__ nf,
                                                    const float* __restrict__ Wn,
                                                    const int* __restrict__ ntype,
                                                    bf16* __restrict__ xout,
                                                    int* __restrict__ cnt) {
    __shared__ float Ws[2 * 64 * 64];   // [t][k][j], 32 KB
    __shared__ float As[64][65];        // [row][k], padded
    int tid = threadIdx.x;
    int n0 = blockIdx.x * 64;
    {   // fused cnt zeroing (1563*256 = 400128 >= NK)
        int zi = blockIdx.x * 256 + tid;
        if (zi < NK) cnt[zi] = 0;
    }
    for (int i = tid; i < 2 * 64 * 64; i += 256) Ws[i] = Wn[i];
#pragma unroll
    for (int i = 0; i < 4; ++i) {
        int f = (i * 256 + tid) * 4;
        int r = f >> 6, c = f & 63;
        int n = n0 + r;
        float4 v = (n < N_NODES) ? *(const float4*)&nf[(size_t)n * 64 + c]
                                 : make_float4(0.f, 0.f, 0.f, 0.f);
        As[r][c + 0] = v.x; As[r][c + 1] = v.y; As[r][c + 2] = v.z; As[r][c + 3] = v.w;
    }
    __syncthreads();
    int tx = tid & 15, ty = tid >> 4;
    int r0 = n0 + ty * 4;
    int t0 = (r0 + 0 < N_NODES) ? ntype[r0 + 0] : 0;
    int t1 = (r0 + 1 < N_NODES) ? ntype[r0 + 1] : 0;
    int t2 = (r0 + 2 < N_NODES) ? ntype[r0 + 2] : 0;
    int t3 = (r0 + 3 < N_NODES) ? ntype[r0 + 3] : 0;
    float4 acc0 = {0,0,0,0}, acc1 = {0,0,0,0}, acc2 = {0,0,0,0}, acc3 = {0,0,0,0};
#pragma unroll 8
    for (int k = 0; k < 64; ++k) {
        float4 w0 = *(const float4*)&Ws[k * 64 + tx * 4];
        float4 w1 = *(const float4*)&Ws[4096 + k * 64 + tx * 4];
        float a0 = As[ty * 4 + 0][k];
        float a1 = As[ty * 4 + 1][k];
        float a2 = As[ty * 4 + 2][k];
        float a3 = As[ty * 4 + 3][k];
        float4 wa = t0 ? w1 : w0;
        float4 wb = t1 ? w1 : w0;
        float4 wc = t2 ? w1 : w0;
        float4 wd = t3 ? w1 : w0;
        acc0.x = fmaf(a0, wa.x, acc0.x); acc0.y = fmaf(a0, wa.y, acc0.y);
        acc0.z = fmaf(a0, wa.z, acc0.z); acc0.w = fmaf(a0, wa.w, acc0.w);
        acc1.x = fmaf(a1, wb.x, acc1.x); acc1.y = fmaf(a1, wb.y, acc1.y);
        acc1.z = fmaf(a1, wb.z, acc1.z); acc1.w = fmaf(a1, wb.w, acc1.w);
        acc2.x = fmaf(a2, wc.x, acc2.x); acc2.y = fmaf(a2, wc.y, acc2.y);
        acc2.z = fmaf(a2, wc.z, acc2.z); acc2.w = fmaf(a2, wc.w, acc2.w);
        acc3.x = fmaf(a3, wd.x, acc3.x); acc3.y = fmaf(a3, wd.y, acc3.y);
        acc3.z = fmaf(a3, wd.z, acc3.z); acc3.w = fmaf(a3, wd.w, acc3.w);
    }
#pragma unroll
    for (int r = 0; r < 4; ++r) {
        int n = r0 + r;
        if (n < N_NODES) {
            float4 a = (r == 0) ? acc0 : (r == 1) ? acc1 : (r == 2) ? acc2 : acc3;
            union { bf16 h[4]; uint2 u; } pk;
            pk.h[0] = __float2bfloat16(a.x); pk.h[1] = __float2bfloat16(a.y);
            pk.h[2] = __float2bfloat16(a.z); pk.h[3] = __float2bfloat16(a.w);
            *(uint2*)&xout[(size_t)n * 64 + tx * 4] = pk.u;
        }
    }
}

// ---------------------------------------------------------------------------
// count + rank: 1 edge/thread (max atomic parallelism; rank store coalesced)
// ---------------------------------------------------------------------------
__global__ __launch_bounds__(256) void count_rank(const int* __restrict__ eidx,
                                                  const int* __restrict__ etype,
                                                  int* __restrict__ cnt,
                                                  u8* __restrict__ rank) {
    int i = blockIdx.x * 256 + threadIdx.x;
    if (i >= N_EDGES) return;
    int d = eidx[N_EDGES + i];
    int t = etype[i];
    int r = atomicAdd(&cnt[4 * d + t], 1);
    rank[i] = (u8)r;
}

__global__ __launch_bounds__(256) void scan_a(const int* __restrict__ cnt,
                                              int* __restrict__ partials) {
    __shared__ int ws[4];
    int b = blockIdx.x, tid = threadIdx.x, lane = tid & 63, wid = tid >> 6;
    int i0 = b * 1024 + tid * 4;
    int s = 0;
#pragma unroll
    for (int k = 0; k < 4; ++k) { int i = i0 + k; if (i < NK) s += cnt[i]; }
#pragma unroll
    for (int d = 32; d > 0; d >>= 1) s += __shfl_down(s, d);
    if (lane == 0) ws[wid] = s;
    __syncthreads();
    if (tid == 0) partials[b] = ws[0] + ws[1] + ws[2] + ws[3];
}

__global__ __launch_bounds__(512) void scan_b(int* __restrict__ partials) {
    __shared__ int s[512];
    int tid = threadIdx.x;
    int v = (tid < NBCHUNK) ? partials[tid] : 0;
    s[tid] = v;
    __syncthreads();
    for (int d = 1; d < 512; d <<= 1) {
        int u = (tid >= d) ? s[tid - d] : 0;
        __syncthreads();
        s[tid] += u;
        __syncthreads();
    }
    if (tid < NBCHUNK) partials[tid] = s[tid] - v;   // exclusive
}

__global__ __launch_bounds__(256) void scan_c(const int* __restrict__ cnt,
                                              const int* __restrict__ partials,
                                              int* __restrict__ offs) {
    __shared__ int wsum[4];
    int b = blockIdx.x, tid = threadIdx.x, lane = tid & 63, wid = tid >> 6;
    int i0 = b * 1024 + tid * 4;
    int c0 = (i0 + 0 < NK) ? cnt[i0 + 0] : 0;
    int c1 = (i0 + 1 < NK) ? cnt[i0 + 1] : 0;
    int c2 = (i0 + 2 < NK) ? cnt[i0 + 2] : 0;
    int c3 = (i0 + 3 < NK) ? cnt[i0 + 3] : 0;
    int lsum = c0 + c1 + c2 + c3;
    int v = lsum;
#pragma unroll
    for (int d = 1; d < 64; d <<= 1) {
        int u = __shfl_up(v, d);
        if (lane >= d) v += u;
    }
    int wexcl = v - lsum;
    if (lane == 63) wsum[wid] = v;
    __syncthreads();
    int bexcl = 0;
    for (int w = 0; w < wid; ++w) bexcl += wsum[w];
    int base = partials[b] + bexcl + wexcl;
    if (i0 + 0 < NK) offs[i0 + 0] = base; base += c0;
    if (i0 + 1 < NK) offs[i0 + 1] = base; base += c1;
    if (i0 + 2 < NK) offs[i0 + 2] = base; base += c2;
    if (i0 + 3 < NK) offs[i0 + 3] = base;
}

// ---------------------------------------------------------------------------
// place_pay: 8B payload scatter (pos = offs[key]+rank, no atomics),
// one edge per thread (max MLP).
// ---------------------------------------------------------------------------
__global__ __launch_bounds__(256) void place_pay(const int* __restrict__ eidx,
                                                 const int* __restrict__ etype,
                                                 const u8* __restrict__ rank,
                                                 const int* __restrict__ offs,
                                                 u64* __restrict__ pay) {
    int i = blockIdx.x * 256 + threadIdx.x;
    if (i >= N_EDGES) return;
    int d = eidx[N_EDGES + i];
    int s = eidx[i];
    int t = etype[i];
    int pos = offs[4 * d + t] + (int)rank[i];
    pay[pos] = (u64)(unsigned)s | ((u64)(unsigned)i << 32);
}

// ---------------------------------------------------------------------------
// aggregate_g: grid-strided wave/node, PAIRED loads (2 rows per wave-load),
// 16-edge inner step with 8+8 loads hoisted. SOFTWARE PIPELINE: the NEXT
// node's offs AND first pay-chunk are issued before the current node's
// accumulate, overlapping the two longest latency chains. Zero atomics.
// ---------------------------------------------------------------------------
__global__ __launch_bounds__(256) void aggregate_g(const u64* __restrict__ pay,
                                                   const int* __restrict__ offs,
                                                   const bf16* __restrict__ xout,
                                                   const float* __restrict__ ef,
                                                   bf16* __restrict__ B) {
    int wid = threadIdx.x >> 6, lane = threadIdx.x & 63;
    int gw = blockIdx.x * 4 + wid, nw = gridDim.x * 4;
    int c = lane & 31, half = lane >> 5;
    const unsigned short* xo = (const unsigned short*)xout;
    if (gw >= N_NODES) return;

    // preload node gw's offs + first pay chunk
    int4 o = ((const int4*)offs)[gw];
    {
        int b0 = __builtin_amdgcn_readfirstlane(o.x);
        int e0 = __builtin_amdgcn_readfirstlane(o.w);
        // fallthrough preload below uses these
        (void)b0; (void)e0;
    }
    u64 p = 0ull;
    {
        int beg = __builtin_amdgcn_readfirstlane(o.x);
        int end = __builtin_amdgcn_readfirstlane(o.w);
        if (beg + lane < end) p = pay[beg + lane];
    }

    for (int n = gw; n < N_NODES; n += nw) {
        int nn = n + nw;
        int4 onext = make_int4(0, 0, 0, 0);
        u64 pnext = 0ull;
        if (nn < N_NODES) {
            onext = ((const int4*)offs)[nn];
            int nbeg = __builtin_amdgcn_readfirstlane(onext.x);
            int nend = __builtin_amdgcn_readfirstlane(onext.w);
            if (nbeg + lane < nend) pnext = pay[nbeg + lane];   // overlaps this node's compute
        }
        int beg = __builtin_amdgcn_readfirstlane(o.x);
        int y   = __builtin_amdgcn_readfirstlane(o.y);
        int z   = __builtin_amdgcn_readfirstlane(o.z);
        int end = __builtin_amdgcn_readfirstlane(o.w);
        float xa0 = 0.f, xa1 = 0.f, xb0 = 0.f, xb1 = 0.f, xc0 = 0.f, xc1 = 0.f;
        float ea = 0.f, eb = 0.f, ec = 0.f;

        u64 pcur = p;
        for (int base = beg; base < end; base += 64) {
            int m = end - base; if (m > 64) m = 64;
            if (base != beg) pcur = (lane < m) ? pay[base + lane] : 0ull;  // rare (deg>64)
            int plo = (int)(unsigned)pcur;            // src
            int phi = (int)(unsigned)(pcur >> 32);    // edge id
            for (int j = 0; j < m; j += 16) {
                int sgp[8], egp[8];
#pragma unroll
                for (int q = 0; q < 8; ++q) {
                    int a  = __builtin_amdgcn_readlane(plo, j + 2 * q);
                    int b2 = __builtin_amdgcn_readlane(plo, j + 2 * q + 1);
                    sgp[q] = half ? b2 : a;
                    a  = __builtin_amdgcn_readlane(phi, j + 2 * q);
                    b2 = __builtin_amdgcn_readlane(phi, j + 2 * q + 1);
                    egp[q] = half ? b2 : a;
                }
                unsigned xv[8];
                float evv[8];
#pragma unroll
                for (int q = 0; q < 8; ++q) {
                    xv[q]  = *(const unsigned*)(xo + (size_t)sgp[q] * 64 + c * 2);
                    evv[q] = ef[(size_t)egp[q] * 32 + c];
                }
#pragma unroll
                for (int q = 0; q < 8; ++q) {
                    float xl = bflo(xv[q]), xh = bfhi(xv[q]);
                    float ev = evv[q];
                    int i0 = base + j + 2 * q;     // scalar
                    if (i0 + 1 < y) {                                   // pair in seg0
                        xa0 += xl; xa1 += xh; ea += ev;
                    } else if (i0 >= y && i0 + 1 < z) {                 // pair in seg1
                        xb0 += xl; xb1 += xh; eb += ev;
                    } else if (i0 >= z && i0 + 1 < end) {               // pair in seg2
                        xc0 += xl; xc1 += xh; ec += ev;
                    } else {                                            // boundary / tail
                        int idx = i0 + half;
                        bool v = idx < end;
                        float fl = v ? xl : 0.f, fh = v ? xh : 0.f, fe = v ? ev : 0.f;
                        if (idx < y)      { xa0 += fl; xa1 += fh; ea += fe; }
                        else if (idx < z) { xb0 += fl; xb1 += fh; eb += fe; }
                        else              { xc0 += fl; xc1 += fh; ec += fe; }
                    }
                }
            }
        }
        // fold the two halves
        xa0 += __shfl_down(xa0, 32); xa1 += __shfl_down(xa1, 32);
        xb0 += __shfl_down(xb0, 32); xb1 += __shfl_down(xb1, 32);
        xc0 += __shfl_down(xc0, 32); xc1 += __shfl_down(xc1, 32);
        ea  += __shfl_down(ea, 32);  eb  += __shfl_down(eb, 32);  ec += __shfl_down(ec, 32);

        if (lane < 32) {
            bf16* Bn = B + (size_t)n * KCAT;
            *(unsigned*)&Bn[2 * c]       = packbf2(xa0, xa1);
            *(unsigned*)&Bn[64 + 2 * c]  = packbf2(xb0, xb1);
            *(unsigned*)&Bn[128 + 2 * c] = packbf2(xc0, xc1);
            Bn[192 + c] = __float2bfloat16(ea);
            Bn[224 + c] = __float2bfloat16(eb);
            Bn[256 + c] = __float2bfloat16(ec);
        }
        o = onext;
        p = pnext;
    }
}

// ---------------------------------------------------------------------------
// K3: out = B(bf16) @ Wcat(fp32), Wcat[288][64] remapped from W_msg on load.
// Vectorized B staging: one uint4 (8 bf16) per thread -> fp32 LDS.
// ---------------------------------------------------------------------------
__global__ __launch_bounds__(256) void final_gemm(const bf16* __restrict__ B,
                                                  const float* __restrict__ Wm,
                                                  float* __restrict__ out) {
    __shared__ float As[64][36];   // row stride 144B (16B-aligned, 2-way bank = free)
    __shared__ float Ws[32][64];
    int tid = threadIdx.x;
    int n0 = blockIdx.x * 64;
    int tx = tid & 15;
    int ty = tid >> 4;
    float acc[4][4] = {};

    for (int k0 = 0; k0 < KCAT; k0 += 32) {
        // stage A tile [64 nodes][32 k]: uint4 = 8 bf16 per thread
        {
            int r = tid >> 2, cb = (tid & 3) * 8;
            int n = n0 + r;
            uint4 v = make_uint4(0u, 0u, 0u, 0u);
            if (n < N_NODES) v = *(const uint4*)&B[(size_t)n * KCAT + k0 + cb];
            *(float4*)&As[r][cb]     = make_float4(bflo(v.x), bfhi(v.x), bflo(v.y), bfhi(v.y));
            *(float4*)&As[r][cb + 4] = make_float4(bflo(v.z), bfhi(v.z), bflo(v.w), bfhi(v.w));
        }
        // stage W tile [32 k][64 j] with Wcat remap, float4 per thread x2
#pragma unroll
        for (int i = 0; i < 2; ++i) {
            int f = (i * 256 + tid) * 4;
            int kk = f >> 6, j = f & 63;
            int r = k0 + kk;
            int t, kin;
            if (r < 192) { t = r >> 6; kin = r & 63; }
            else         { int q = r - 192; t = q >> 5; kin = 64 + (q & 31); }
            *(float4*)&Ws[kk][j] = *(const float4*)&Wm[(t * 96 + kin) * 64 + j];
        }
        __syncthreads();
#pragma unroll
        for (int kk = 0; kk < 32; ++kk) {
            float a0 = As[ty * 4 + 0][kk];
            float a1 = As[ty * 4 + 1][kk];
            float a2 = As[ty * 4 + 2][kk];
            float a3 = As[ty * 4 + 3][kk];
            float4 w = *(const float4*)&Ws[kk][tx * 4];
            acc[0][0] = fmaf(a0, w.x, acc[0][0]); acc[0][1] = fmaf(a0, w.y, acc[0][1]);
            acc[0][2] = fmaf(a0, w.z, acc[0][2]); acc[0][3] = fmaf(a0, w.w, acc[0][3]);
            acc[1][0] = fmaf(a1, w.x, acc[1][0]); acc[1][1] = fmaf(a1, w.y, acc[1][1]);
            acc[1][2] = fmaf(a1, w.z, acc[1][2]); acc[1][3] = fmaf(a1, w.w, acc[1][3]);
            acc[2][0] = fmaf(a2, w.x, acc[2][0]); acc[2][1] = fmaf(a2, w.y, acc[2][1]);
            acc[2][2] = fmaf(a2, w.z, acc[2][2]); acc[2][3] = fmaf(a2, w.w, acc[2][3]);
            acc[3][0] = fmaf(a3, w.x, acc[3][0]); acc[3][1] = fmaf(a3, w.y, acc[3][1]);
            acc[3][2] = fmaf(a3, w.z, acc[3][2]); acc[3][3] = fmaf(a3, w.w, acc[3][3]);
        }
        __syncthreads();
    }
#pragma unroll
    for (int r = 0; r < 4; ++r) {
        int n = n0 + ty * 4 + r;
        if (n < N_NODES) {
            float4 v = make_float4(acc[r][0], acc[r][1], acc[r][2], acc[r][3]);
            *(float4*)&out[(size_t)n * 64 + tx * 4] = v;
        }
    }
}

// ---------------------------------------------------------------------------
// Fallback (ws tiny): direct wave-per-edge, fp32.
// ---------------------------------------------------------------------------
__global__ __launch_bounds__(256) void fallback_edge(const float* __restrict__ nf,
                                                     const float* __restrict__ ef,
                                                     const float* __restrict__ Wn,
                                                     const float* __restrict__ Wm,
                                                     const int* __restrict__ ntype,
                                                     const int* __restrict__ etype,
                                                     const int* __restrict__ eidx,
                                                     float* __restrict__ out) {
    __shared__ float wn[2 * 64 * 64];
    __shared__ float wm[3 * 96 * 64];
    for (int i = threadIdx.x; i < 2 * 64 * 64; i += 256) wn[i] = Wn[i];
    for (int i = threadIdx.x; i < 3 * 96 * 64; i += 256) wm[i] = Wm[i];
    __syncthreads();
    int wid = threadIdx.x >> 6, lane = threadIdx.x & 63;
    for (int e = blockIdx.x * 4 + wid; e < N_EDGES; e += gridDim.x * 4) {
        int t = etype[e];
        int s = eidx[e];
        int d = eidx[N_EDGES + e];
        int nt = ntype[s];
        float xs = nf[(long)s * 64 + lane];
        const float* wcol = &wn[nt * 4096 + lane];
        float xo = 0.f;
#pragma unroll 16
        for (int k = 0; k < 64; ++k) xo = fmaf(__shfl(xs, k), wcol[k * 64], xo);
        float ev = ef[(long)e * 32 + (lane & 31)];
        const float* mcol = &wm[t * 96 * 64 + lane];
        float m = 0.f;
#pragma unroll 16
        for (int k = 0; k < 64; ++k) m = fmaf(__shfl(xo, k), mcol[k * 64], m);
#pragma unroll 8
        for (int k = 0; k < 32; ++k) m = fmaf(__shfl(ev, k), mcol[(64 + k) * 64], m);
        atomicAdd(&out[(long)d * 64 + lane], m);
    }
}

// ---------------------------------------------------------------------------
extern "C" void kernel_launch(void* const* d_in, const int* in_sizes, int n_in,
                              void* d_out, int out_size, void* d_ws, size_t ws_size,
                              hipStream_t stream) {
    const float* nf    = (const float*)d_in[0];
    const float* ef    = (const float*)d_in[1];
    const float* Wn    = (const float*)d_in[2];
    const float* Wm    = (const float*)d_in[3];
    const int*   ntype = (const int*)d_in[4];
    const int*   etype = (const int*)d_in[5];
    const int*   eidx  = (const int*)d_in[6];
    float* out = (float*)d_out;

    const size_t xout_bytes = (size_t)N_NODES * 64 * 2;        // 12.8 MB bf16
    const size_t b_bytes    = (size_t)N_NODES * KCAT * 2;      // 57.6 MB bf16

    if (ws_size >= xout_bytes + b_bytes) {
        bf16* xout = (bf16*)d_ws;
        bf16* B    = (bf16*)((char*)d_ws + xout_bytes);
        // scratch in d_out (17.6 MB < 25.6 MB); final_gemm fully overwrites
        // d_out at the end of every call.
        u64* pay      = (u64*)d_out;            // 12.8 MB
        int* cnt      = (int*)(pay + N_EDGES);  // 1.6 MB
        int* offs     = cnt + NK;               // 1.6 MB
        int* partials = offs + NK;              // 2 KB (pad 512)
        u8*  rank     = (u8*)(partials + 512);  // 1.6 MB

        node_xform_g<<<(N_NODES + 63) / 64, 256, 0, stream>>>(nf, Wn, ntype, xout, cnt);
        count_rank<<<(N_EDGES + 255) / 256, 256, 0, stream>>>(eidx, etype, cnt, rank);
        scan_a<<<NBCHUNK, 256, 0, stream>>>(cnt, partials);
        scan_b<<<1, 512, 0, stream>>>(partials);
        scan_c<<<NBCHUNK, 256, 0, stream>>>(cnt, partials, offs);
        place_pay<<<(N_EDGES + 255) / 256, 256, 0, stream>>>(eidx, etype, rank, offs, pay);
        aggregate_g<<<4096, 256, 0, stream>>>(pay, offs, xout, ef, B);
        final_gemm<<<(N_NODES + 63) / 64, 256, 0, stream>>>(B, Wm, out);
    } else {
        zero_buf<<<2048, 256, 0, stream>>>((float4*)d_out, (long)((size_t)out_size * 4 / 16));
        fallback_edge<<<4096, 256, 0, stream>>>(nf, ef, Wn, Wm, ntype, etype, eidx, out);
    }
}